// Round 9
// baseline (805.698 us; speedup 1.0000x reference)
//
#include <hip/hip_runtime.h>
#include <hip/hip_bf16.h>

#define B_   32
#define M_   512
#define E_   512
#define S_   513            // M+1
#define T_   (B_ * S_)      // 16416 tokens
#define TP_  16512          // 129*128 padded
#define NH_  8
#define DH_  64
#define F_   768
#define DFF_ 2048

#define GMT_ 129            // m tiles

typedef short short8 __attribute__((ext_vector_type(8)));
typedef float floatx4 __attribute__((ext_vector_type(4)));

__device__ __forceinline__ float bf2f(unsigned short u) {
    return __uint_as_float(((unsigned int)u) << 16);
}
__device__ __forceinline__ unsigned short f2b_rne(float f) {
    unsigned int u = __float_as_uint(f);
    unsigned int r = u + 0x7FFF + ((u >> 16) & 1);
    return (unsigned short)(r >> 16);
}
__device__ __forceinline__ void gload16(const void* g, void* l) {
    __builtin_amdgcn_global_load_lds(
        (const __attribute__((address_space(1))) void*)g,
        (__attribute__((address_space(3))) void*)l, 16, 0, 0);
}
// gfx9 s_waitcnt imm: vmcnt[3:0], expcnt[6:4]=7 (none), lgkmcnt[11:8]=0xF (none)
__device__ __forceinline__ void wait_vm0() { __builtin_amdgcn_s_waitcnt(0x0F70); }
__device__ __forceinline__ void wait_vm4() { __builtin_amdgcn_s_waitcnt(0x0F74); }

// ---------------------------------------------------------------- span ids
__global__ void span_kernel(const int* __restrict__ pos1, int* __restrict__ span) {
    int b = blockIdx.x;
    __shared__ int st[M_], en[M_];
    __shared__ int nv;
    int tid = threadIdx.x;
    for (int j = tid; j < M_; j += 256) {
        st[j] = pos1[(b * M_ + j) * 2];
        en[j] = pos1[(b * M_ + j) * 2 + 1];
    }
    __syncthreads();
    if (tid == 0) {
        int n = M_;
        for (int j = 0; j < M_; ++j) if (en[j] == 0) { n = j; break; }
        nv = n;
    }
    __syncthreads();
    int n = nv;
    for (int k = tid; k < M_; k += 256) {
        int best = -1;
        for (int j = 0; j < n; ++j)
            if (st[j] <= k && k < en[j]) best = j;
        span[b * M_ + k] = best;
    }
}

// ---------------------------------------------------------------- f32 -> bf16, 5 fused segments, x4 vectorized
__global__ void f2b5_kernel(const float* __restrict__ s0, const float* __restrict__ s1,
                            const float* __restrict__ s2, const float* __restrict__ s3,
                            const float* __restrict__ s4,
                            unsigned short* __restrict__ dst,
                            int c0, int c1, int c2, int c3, int c4) {
    int i = (blockIdx.x * 256 + threadIdx.x) * 4;
    if (i >= c4) return;
    const float* src; int off;
    if      (i < c0) { src = s0; off = i; }
    else if (i < c1) { src = s1; off = i - c0; }
    else if (i < c2) { src = s2; off = i - c1; }
    else if (i < c3) { src = s3; off = i - c2; }
    else             { src = s4; off = i - c3; }
    float4 v = *(const float4*)(src + off);
    ushort4 o;
    o.x = f2b_rne(v.x); o.y = f2b_rne(v.y);
    o.z = f2b_rne(v.z); o.w = f2b_rne(v.w);
    *(ushort4*)(dst + i) = o;
}

// ---------------------------------------------------------------- build x0 (f32 + bf16 shadow), PE inline
__global__ void build_x(const float* __restrict__ emb,
                        const int* __restrict__ pos2,
                        const float* __restrict__ fbase,
                        const int* __restrict__ span,
                        float* __restrict__ x,
                        unsigned short* __restrict__ xb) {
    long long idx = (long long)blockIdx.x * blockDim.x + threadIdx.x;
    if (idx >= (long long)T_ * E_) return;
    int e = (int)(idx % E_);
    int t = (int)(idx / E_);
    int s = t % S_;
    int b = t / S_;
    float val;
    if (s == 0) {
        val = emb[E_ + e];
    } else {
        int k = s - 1;
        int sid = span[b * M_ + k];
        if (sid >= 0) {
            int p = pos2[b * M_ + sid];
            float ex = (float)((e >> 1) << 1) * (1.0f / 512.0f);
            float ang = (float)sid * exp2f(-ex * 13.287712379549449f);  // log2(10000)
            float pe = (e & 1) ? cosf(ang) : sinf(ang);
            val = emb[(size_t)p * E_ + e] + pe;
        } else {
            val = fbase[((size_t)b * M_ + k) * E_ + e];
        }
    }
    x[idx] = val;
    xb[idx] = f2b_rne(val);
}

// ---------------------------------------------------------------- bf16 MFMA GEMM (NT), 3-deep pipelined
// A [TP_,K] bf16, W [O,K] bf16; C = act(A·W^T + bias), bf16 out.
// Block 128x128, 4 waves, wave tile 64x64 (4x4 mfma 16x16x32), BK=32.
// Triple-buffered LDS; per step: wait vmcnt(4) [batch s landed, s+1 in flight]
// -> barrier -> issue batch s+2 -> ds_read+MFMA buf[s%3]. One barrier/step,
// load latency spans two K-steps. Safety: each wave issues exactly 4
// global_load_lds per step, counters retire in order; issue happens after the
// barrier whose crossing proves all readers of the target buffer are done.
template <int ACT, int KT>  // ACT: 0 none 1 relu 2 tanh
__global__ __launch_bounds__(256, 3) void gemm_bf16(const unsigned short* __restrict__ A,
                                                    const unsigned short* __restrict__ W,
                                                    const float* __restrict__ bias,
                                                    unsigned short* __restrict__ Cb,
                                                    int T, int O) {
    constexpr int K = KT;
    constexpr int NSTEP = K / 32;
    __shared__ __align__(16) unsigned short sA[3][128 * 32];
    __shared__ __align__(16) unsigned short sB[3][128 * 32];
    int tid = threadIdx.x;
    int lane = tid & 63, wv = tid >> 6;
    int wr = (wv >> 1) * 64, wc = (wv & 1) * 64;

    // ---- panel swizzle: 8 m-tiles per panel, n fastest within panel
    int gn = O / 128;
    int per_panel = 8 * gn;
    int id = blockIdx.x;
    int p = id / per_panel;
    int r = id - p * per_panel;
    int mrem = GMT_ - p * 8; if (mrem > 8) mrem = 8;
    int mt = p * 8 + r % mrem;
    int nt = r / mrem;
    int t0 = mt * 128, o0 = nt * 128;

    floatx4 acc[4][4] = {};

    const unsigned short* Ag = A + (size_t)(t0 + wv * 32 + (lane >> 2)) * K + (lane & 3) * 8;
    const unsigned short* Bg = W + (size_t)(o0 + wv * 32 + (lane >> 2)) * K + (lane & 3) * 8;
    const size_t row16 = (size_t)16 * K;
    int fr = lane & 15;
    int fk = (lane >> 4) * 8;

    // prologue: batch 0 -> buf0, batch 1 -> buf1
    {
        unsigned short* dA = &sA[0][wv * 1024];
        unsigned short* dB = &sB[0][wv * 1024];
        gload16(Ag, dA);
        gload16(Ag + row16, dA + 512);
        gload16(Bg, dB);
        gload16(Bg + row16, dB + 512);
    }
    {
        unsigned short* dA = &sA[1][wv * 1024];
        unsigned short* dB = &sB[1][wv * 1024];
        gload16(Ag + 32, dA);
        gload16(Ag + row16 + 32, dA + 512);
        gload16(Bg + 32, dB);
        gload16(Bg + row16 + 32, dB + 512);
    }

    int cur = 0, nx2 = 2;
    for (int s = 0; s < NSTEP; ++s) {
        if (s < NSTEP - 1) wait_vm4();   // batch s landed; batch s+1 may fly
        else               wait_vm0();   // final: everything landed
        __syncthreads();

        if (s + 2 < NSTEP) {
            const int k = (s + 2) * 32;
            unsigned short* dA = &sA[nx2][wv * 1024];
            unsigned short* dB = &sB[nx2][wv * 1024];
            gload16(Ag + k, dA);
            gload16(Ag + row16 + k, dA + 512);
            gload16(Bg + k, dB);
            gload16(Bg + row16 + k, dB + 512);
        }

        short8 af[4], bfr[4];
#pragma unroll
        for (int i = 0; i < 4; ++i)
            af[i] = *(const short8*)&sA[cur][(wr + i * 16 + fr) * 32 + fk];
#pragma unroll
        for (int j = 0; j < 4; ++j)
            bfr[j] = *(const short8*)&sB[cur][(wc + j * 16 + fr) * 32 + fk];
#pragma unroll
        for (int i = 0; i < 4; ++i)
#pragma unroll
            for (int j = 0; j < 4; ++j)
                acc[i][j] = __builtin_amdgcn_mfma_f32_16x16x32_bf16(af[i], bfr[j], acc[i][j], 0, 0, 0);

        cur = (cur == 2) ? 0 : cur + 1;
        nx2 = (nx2 == 2) ? 0 : nx2 + 1;
    }

    int cr = (lane >> 4) * 4;
    int cc = lane & 15;
#pragma unroll
    for (int i = 0; i < 4; ++i) {
#pragma unroll
        for (int j = 0; j < 4; ++j) {
            int gn_ = o0 + wc + j * 16 + cc;
            float bv = bias ? bias[gn_] : 0.f;
#pragma unroll
            for (int rr = 0; rr < 4; ++rr) {
                int gm_ = t0 + wr + i * 16 + cr + rr;
                if (gm_ >= T) continue;
                float v = acc[i][j][rr] + bv;
                if (ACT == 1) v = fmaxf(v, 0.f);
                if (ACT == 2) v = tanhf(v);
                Cb[(size_t)gm_ * O + gn_] = f2b_rne(v);
            }
        }
    }
}

// ---------------------------------------------------------------- MFMA attention: one wave per (s,h)
__global__ __launch_bounds__(64) void attn_mfma(const unsigned short* __restrict__ qkv,
                                                unsigned short* __restrict__ o) {
    __shared__ __align__(16) unsigned short vt[64 * 40];   // V^T [d][m], stride 40
    __shared__ __align__(16) unsigned short ps[32 * 40];   // P [l][m], stride 40
    int s = blockIdx.x, h = blockIdx.y;
    int lane = threadIdx.x;
    int hd = h * 64;
    int fr = lane & 15, fq = lane >> 4;

    {
        int m = lane >> 1;
        int d0 = (lane & 1) * 32;
        const unsigned short* vrow = qkv + ((size_t)m * S_ + s) * 1536 + 1024 + hd + d0;
        short8 v0 = *(const short8*)(vrow);
        short8 v1 = *(const short8*)(vrow + 8);
        short8 v2 = *(const short8*)(vrow + 16);
        short8 v3 = *(const short8*)(vrow + 24);
#pragma unroll
        for (int j = 0; j < 8; ++j) {
            vt[(d0 + j) * 40 + m]      = (unsigned short)v0[j];
            vt[(d0 + 8 + j) * 40 + m]  = (unsigned short)v1[j];
            vt[(d0 + 16 + j) * 40 + m] = (unsigned short)v2[j];
            vt[(d0 + 24 + j) * 40 + m] = (unsigned short)v3[j];
        }
    }

    floatx4 c[2][2] = {};
#pragma unroll
    for (int ks = 0; ks < 2; ++ks) {
        short8 aq[2], bk[2];
#pragma unroll
        for (int lt = 0; lt < 2; ++lt) {
            int l = lt * 16 + fr;
            aq[lt] = *(const short8*)(qkv + ((size_t)l * S_ + s) * 1536 + hd + ks * 32 + fq * 8);
        }
#pragma unroll
        for (int mt = 0; mt < 2; ++mt) {
            int m = mt * 16 + fr;
            bk[mt] = *(const short8*)(qkv + ((size_t)m * S_ + s) * 1536 + 512 + hd + ks * 32 + fq * 8);
        }
#pragma unroll
        for (int lt = 0; lt < 2; ++lt)
#pragma unroll
            for (int mt = 0; mt < 2; ++mt)
                c[lt][mt] = __builtin_amdgcn_mfma_f32_16x16x32_bf16(aq[lt], bk[mt], c[lt][mt], 0, 0, 0);
    }

#pragma unroll
    for (int lt = 0; lt < 2; ++lt) {
#pragma unroll
        for (int r = 0; r < 4; ++r) {
            float a = c[lt][0][r] * 0.125f;
            float b = c[lt][1][r] * 0.125f;
            float mx = fmaxf(a, b);
#pragma unroll
            for (int off = 1; off < 16; off <<= 1) mx = fmaxf(mx, __shfl_xor(mx, off));
            float ea = expf(a - mx), eb = expf(b - mx);
            float sm = ea + eb;
#pragma unroll
            for (int off = 1; off < 16; off <<= 1) sm += __shfl_xor(sm, off);
            float inv = 1.f / sm;
            int l = lt * 16 + fq * 4 + r;
            ps[l * 40 + fr]      = f2b_rne(ea * inv);
            ps[l * 40 + 16 + fr] = f2b_rne(eb * inv);
        }
    }
    __syncthreads();

    short8 pa[2], vb[4];
#pragma unroll
    for (int lt = 0; lt < 2; ++lt)
        pa[lt] = *(const short8*)&ps[(lt * 16 + fr) * 40 + fq * 8];
#pragma unroll
    for (int dt = 0; dt < 4; ++dt)
        vb[dt] = *(const short8*)&vt[(dt * 16 + fr) * 40 + fq * 8];

    floatx4 oa[2][4] = {};
#pragma unroll
    for (int lt = 0; lt < 2; ++lt)
#pragma unroll
        for (int dt = 0; dt < 4; ++dt)
            oa[lt][dt] = __builtin_amdgcn_mfma_f32_16x16x32_bf16(pa[lt], vb[dt], oa[lt][dt], 0, 0, 0);

#pragma unroll
    for (int lt = 0; lt < 2; ++lt)
#pragma unroll
        for (int dt = 0; dt < 4; ++dt)
#pragma unroll
            for (int r = 0; r < 4; ++r) {
                int l = lt * 16 + fq * 4 + r;
                o[((size_t)l * S_ + s) * E_ + hd + dt * 16 + fr] = f2b_rne(oa[lt][dt][r]);
            }
}

// ---------------------------------------------------------------- x = LN(x + h); h in bf16; writes f32 + bf16 shadow
__global__ __launch_bounds__(256) void add_ln(float* __restrict__ x,
                                              unsigned short* __restrict__ xb,
                                              const unsigned short* __restrict__ h,
                                              const float* __restrict__ w,
                                              const float* __restrict__ b) {
    int t = blockIdx.x;
    float* xr = x + (size_t)t * E_;
    const unsigned short* hr = h + (size_t)t * E_;
    int i0 = threadIdx.x * 2;
    float2 xv = *(const float2*)&xr[i0];
    ushort2 hv = *(const ushort2*)&hr[i0];
    float v0 = xv.x + bf2f(hv.x), v1 = xv.y + bf2f(hv.y);

    __shared__ float red[4];
    float sum = v0 + v1;
    for (int off = 32; off; off >>= 1) sum += __shfl_down(sum, off);
    if ((threadIdx.x & 63) == 0) red[threadIdx.x >> 6] = sum;
    __syncthreads();
    float mu = (red[0] + red[1] + red[2] + red[3]) * (1.0f / E_);
    __syncthreads();

    float d0 = v0 - mu, d1 = v1 - mu;
    float qs = d0 * d0 + d1 * d1;
    for (int off = 32; off; off >>= 1) qs += __shfl_down(qs, off);
    if ((threadIdx.x & 63) == 0) red[threadIdx.x >> 6] = qs;
    __syncthreads();
    float var = (red[0] + red[1] + red[2] + red[3]) * (1.0f / E_);
    float rstd = rsqrtf(var + 1e-5f);

    float o0 = d0 * rstd * w[i0]     + b[i0];
    float o1 = d1 * rstd * w[i0 + 1] + b[i0 + 1];
    *(float2*)&xr[i0] = make_float2(o0, o1);
    xb[(size_t)t * E_ + i0]     = f2b_rne(o0);
    xb[(size_t)t * E_ + i0 + 1] = f2b_rne(o1);
}

// ---------------------------------------------------------------- discriminator + sigmoid (pf in bf16)
__global__ __launch_bounds__(256) void disc_kernel(const float* __restrict__ bert,
                                                   const unsigned short* __restrict__ pf,
                                                   const float* __restrict__ wd,
                                                   const float* __restrict__ bd,
                                                   float* __restrict__ out) {
    int t = blockIdx.x;
    float s = 0.f;
    for (int f = threadIdx.x; f < F_; f += 256) {
        s += bert[(size_t)t * F_ + f] * wd[f];
        s += bf2f(pf[(size_t)t * F_ + f]) * wd[F_ + f];
    }
    for (int off = 32; off; off >>= 1) s += __shfl_down(s, off);
    __shared__ float red[4];
    if ((threadIdx.x & 63) == 0) red[threadIdx.x >> 6] = s;
    __syncthreads();
    if (threadIdx.x == 0) {
        float z = red[0] + red[1] + red[2] + red[3] + bd[0];
        out[t] = 1.f / (1.f + expf(-z));
    }
}

// ---------------------------------------------------------------- launch
extern "C" void kernel_launch(void* const* d_in, const int* in_sizes, int n_in,
                              void* d_out, int out_size, void* d_ws, size_t ws_size,
                              hipStream_t stream) {
    const int*   pos1 = (const int*)d_in[0];
    const int*   pos2 = (const int*)d_in[1];
    const float* bert = (const float*)d_in[2];
    const float* fb   = (const float*)d_in[3];
    const float* emb  = (const float*)d_in[4];
    const float* wi   = (const float*)d_in[5];
    const float* bi   = (const float*)d_in[6];
    const float* wo   = (const float*)d_in[7];
    const float* bo   = (const float*)d_in[8];
    const float* ln1w = (const float*)d_in[9];
    const float* ln1b = (const float*)d_in[10];
    const float* ln2w = (const float*)d_in[11];
    const float* ln2b = (const float*)d_in[12];
    const float* w1   = (const float*)d_in[13];
    const float* b1   = (const float*)d_in[14];
    const float* w2   = (const float*)d_in[15];
    const float* b2   = (const float*)d_in[16];
    const float* wm   = (const float*)d_in[17];
    const float* wd   = (const float*)d_in[18];
    const float* bd   = (const float*)d_in[19];
    float* out = (float*)d_out;

    // workspace layout
    float* ws   = (float*)d_ws;
    int*   span = (int*)ws;                                   // 16384 i
    float* x    = ws + 16384;                                 // T_*512 f
    unsigned short* xb  = (unsigned short*)(x + (size_t)T_ * 512);   // TP_*512 bf16
    unsigned short* atb = xb + (size_t)TP_ * 512;                    // TP_*512 bf16
    unsigned short* hb  = atb + (size_t)TP_ * 512;                   // T_*512 bf16
    unsigned short* U   = hb + (size_t)T_ * 512;              // union: qkv | h1 | pf
    unsigned short* qkvb = U;
    unsigned short* h1b  = U;
    unsigned short* pfb  = U;
    unsigned short* wib  = U + (size_t)TP_ * 2048;            // weights bf16, contiguous
    const int NWI = 2 * 1536 * 512;
    const int NWO = 2 * 512 * 512;
    const int NW1 = 2 * 2048 * 512;
    const int NW2 = 2 * 512 * 2048;
    const int NWM = 768 * 512;
    unsigned short* wob = wib + NWI;
    unsigned short* w1b = wob + NWO;
    unsigned short* w2b = w1b + NW1;
    unsigned short* wmb = w2b + NW2;

    span_kernel<<<B_, 256, 0, stream>>>(pos1, span);
    {
        int c0 = NWI, c1 = c0 + NWO, c2 = c1 + NW1, c3 = c2 + NW2, c4 = c3 + NWM;
        f2b5_kernel<<<(c4 / 4 + 255) / 256, 256, 0, stream>>>(wi, wo, w1, w2, wm, wib,
                                                              c0, c1, c2, c3, c4);
    }
    build_x<<<(int)(((long long)T_ * 512 + 255) / 256), 256, 0, stream>>>(emb, pos2, fb, span, x, xb);

    for (int l = 0; l < 2; ++l) {
        gemm_bf16<0, 512><<<GMT_ * (1536 / 128), 256, 0, stream>>>(
            xb, wib + (size_t)l * 1536 * 512, bi + l * 1536, qkvb, T_, 1536);
        attn_mfma<<<dim3(S_, NH_), 64, 0, stream>>>(qkvb, atb);
        gemm_bf16<0, 512><<<GMT_ * (512 / 128), 256, 0, stream>>>(
            atb, wob + (size_t)l * 512 * 512, bo + l * 512, hb, T_, 512);
        add_ln<<<T_, 256, 0, stream>>>(x, xb, hb, ln1w + l * 512, ln1b + l * 512);
        gemm_bf16<1, 512><<<GMT_ * (2048 / 128), 256, 0, stream>>>(
            xb, w1b + (size_t)l * 2048 * 512, b1 + l * 2048, h1b, T_, 2048);
        gemm_bf16<0, 2048><<<GMT_ * (512 / 128), 256, 0, stream>>>(
            h1b, w2b + (size_t)l * 512 * 2048, b2 + l * 512, hb, T_, 512);
        add_ln<<<T_, 256, 0, stream>>>(x, xb, hb, ln2w + l * 512, ln2b + l * 512);
    }
    gemm_bf16<2, 512><<<GMT_ * (768 / 128), 256, 0, stream>>>(
        xb, wmb, nullptr, pfb, T_, 768);
    disc_kernel<<<T_, 256, 0, stream>>>(bert, pfb, wd, bd, out);
}